// Round 1
// baseline (1101.314 us; speedup 1.0000x reference)
//
#include <hip/hip_runtime.h>
#include <hip/hip_bf16.h>

#define B_SZ 8192
#define L_SZ 64
#define D_SZ 256
#define NC   600
#define MAXF 128
#define CAP  64     // max samples per clan bucket (expected max ~28)

// ---------------- mean over L: x[b,d] = mean_l output[b,l,d] ----------------
__global__ __launch_bounds__(256) void mean_kernel(const float* __restrict__ out,
                                                   float* __restrict__ x) {
    int gid = blockIdx.x * 256 + threadIdx.x;      // B*D/4 = 524288 threads
    int b = gid >> 6, d4 = gid & 63;
    const float4* p = (const float4*)(out + (size_t)b * L_SZ * D_SZ) + d4;
    float4 acc = {0.f, 0.f, 0.f, 0.f};
#pragma unroll 8
    for (int l = 0; l < L_SZ; ++l) {
        float4 v = p[(size_t)l * (D_SZ / 4)];
        acc.x += v.x; acc.y += v.y; acc.z += v.z; acc.w += v.w;
    }
    const float s = 1.0f / 64.0f;
    acc.x *= s; acc.y *= s; acc.z *= s; acc.w *= s;
    ((float4*)(x + (size_t)b * D_SZ))[d4] = acc;
}

// ---------------- bucket samples by clan + count active ----------------
__global__ __launch_bounds__(256) void scatter_kernel(const int* __restrict__ label_clan,
                                                      const int* __restrict__ fc,
                                                      int* __restrict__ cnt,
                                                      int* __restrict__ list,
                                                      int* __restrict__ active_cnt) {
    int b = blockIdx.x * 256 + threadIdx.x;        // grid exactly covers 8192
    int cl = label_clan[b];
    int pos = atomicAdd(&cnt[cl], 1);
    if (pos < CAP) list[cl * CAP + pos] = b;
    int act = (fc[cl] > 1) ? 1 : 0;
    unsigned long long ball = __ballot(act);
    if ((threadIdx.x & 63) == 0) atomicAdd(active_cnt, (int)__popcll(ball));
}

// ---------------- clan GEMM: logits[b,c] = x[b]·W_clan[c] + b_clan[c] ----------------
#define BM 64
#define BN 64
#define BK 32
__global__ __launch_bounds__(256) void clan_gemm(const float* __restrict__ x,
                                                 const float* __restrict__ Wc,
                                                 const float* __restrict__ bc,
                                                 float* __restrict__ logits) {
    __shared__ float As[BM][BK + 4];
    __shared__ float Bs[BN][BK + 4];
    int t = threadIdx.x;
    int tx = t & 15, ty = t >> 4;
    int row0 = blockIdx.x * BM;
    int col0 = blockIdx.y * BN;
    float acc[4][4] = {};
    for (int k0 = 0; k0 < D_SZ; k0 += BK) {
#pragma unroll
        for (int q = t; q < BM * BK / 4; q += 256) {
            int r = q >> 3, c4 = q & 7;
            float4 v = *(const float4*)(x + (size_t)(row0 + r) * D_SZ + k0 + c4 * 4);
            *(float4*)&As[r][c4 * 4] = v;
        }
#pragma unroll
        for (int q = t; q < BN * BK / 4; q += 256) {
            int r = q >> 3, c4 = q & 7;
            int cl = col0 + r;
            float4 v = {0.f, 0.f, 0.f, 0.f};
            if (cl < NC) v = *(const float4*)(Wc + (size_t)cl * D_SZ + k0 + c4 * 4);
            *(float4*)&Bs[r][c4 * 4] = v;
        }
        __syncthreads();
#pragma unroll
        for (int kk = 0; kk < BK; kk += 4) {
            float4 a[4], bb[4];
#pragma unroll
            for (int i = 0; i < 4; ++i) a[i] = *(float4*)&As[ty * 4 + i][kk];
#pragma unroll
            for (int j = 0; j < 4; ++j) bb[j] = *(float4*)&Bs[tx * 4 + j][kk];
#pragma unroll
            for (int i = 0; i < 4; ++i)
#pragma unroll
                for (int j = 0; j < 4; ++j)
                    acc[i][j] += a[i].x * bb[j].x + a[i].y * bb[j].y +
                                 a[i].z * bb[j].z + a[i].w * bb[j].w;
        }
        __syncthreads();
    }
#pragma unroll
    for (int i = 0; i < 4; ++i) {
        int m = row0 + ty * 4 + i;
#pragma unroll
        for (int j = 0; j < 4; ++j) {
            int c = col0 + tx * 4 + j;
            if (c < NC) logits[(size_t)m * NC + c] = acc[i][j] + bc[c];
        }
    }
}

// ---------------- clan loss: sum_b [lse(logits[b]) - logits[b,label]] ----------------
__global__ __launch_bounds__(256) void clan_loss(const float* __restrict__ logits,
                                                 const int* __restrict__ label_clan,
                                                 float* __restrict__ acc_loss) {
    int b = blockIdx.x;
    const float* row = logits + (size_t)b * NC;
    int t = threadIdx.x;
    __shared__ float sred[8];
    float m = -1e30f;
    for (int c = t; c < NC; c += 256) m = fmaxf(m, row[c]);
#pragma unroll
    for (int off = 32; off; off >>= 1) m = fmaxf(m, __shfl_down(m, off));
    if ((t & 63) == 0) sred[t >> 6] = m;
    __syncthreads();
    float bm = fmaxf(fmaxf(sred[0], sred[1]), fmaxf(sred[2], sred[3]));
    float s = 0.f;
    for (int c = t; c < NC; c += 256) s += __expf(row[c] - bm);
#pragma unroll
    for (int off = 32; off; off >>= 1) s += __shfl_down(s, off);
    if ((t & 63) == 0) sred[4 + (t >> 6)] = s;
    __syncthreads();
    if (t == 0) {
        float tot = sred[4] + sred[5] + sred[6] + sred[7];
        float loss = __logf(tot) + bm - row[label_clan[b]];
        atomicAdd(acc_loss, loss);
    }
}

// ---------------- family loss: one block per clan ----------------
#define CHUNK 16
__global__ __launch_bounds__(256) void family_kernel(const float* __restrict__ x,
                                                     const float* __restrict__ Wf,
                                                     const float* __restrict__ bf,
                                                     const int* __restrict__ fc,
                                                     const int* __restrict__ cnt,
                                                     const int* __restrict__ list,
                                                     const int* __restrict__ label_family,
                                                     float* __restrict__ acc_loss) {
    int clan = blockIdx.x;
    int nf = fc[clan];
    if (nf <= 1) return;                    // inactive clans contribute 0
    int n = min(cnt[clan], CAP);
    if (n == 0) return;
    __shared__ float sx[CHUNK][D_SZ];
    __shared__ float slog[CHUNK][MAXF];
    __shared__ int sb[CHUNK];
    int t = threadIdx.x;
    int lane = t & 63, wid = t >> 6;
    const float* Wbase = Wf + (size_t)clan * MAXF * D_SZ;

    for (int s0 = 0; s0 < n; s0 += CHUNK) {
        int cn = min(CHUNK, n - s0);
        if (t < cn) sb[t] = list[clan * CAP + s0 + t];
        __syncthreads();
        for (int q = t; q < cn * (D_SZ / 4); q += 256) {
            int s = q >> 6, d4 = q & 63;
            ((float4*)sx[s])[d4] = ((const float4*)(x + (size_t)sb[s] * D_SZ))[d4];
        }
        __syncthreads();
        // logits: wave `wid` handles families f = wid, wid+4, ...
        for (int f = wid; f < nf; f += 4) {
            float4 w = ((const float4*)(Wbase + (size_t)f * D_SZ))[lane];
            float bias = bf[clan * MAXF + f];
            for (int s = 0; s < cn; ++s) {
                float4 xv = ((float4*)sx[s])[lane];
                float p = w.x * xv.x + w.y * xv.y + w.z * xv.z + w.w * xv.w;
#pragma unroll
                for (int off = 32; off; off >>= 1) p += __shfl_down(p, off);
                if (lane == 0) slog[s][f] = p + bias;
            }
        }
        __syncthreads();
        // softmax + nll per sample; wave wid takes samples wid, wid+4, ...
        float wave_loss = 0.f;
        for (int s = wid; s < cn; s += 4) {
            float v0 = (lane < nf) ? slog[s][lane] : -1e30f;
            float v1 = (lane + 64 < nf) ? slog[s][lane + 64] : -1e30f;
            float m = fmaxf(v0, v1);
#pragma unroll
            for (int off = 32; off; off >>= 1) m = fmaxf(m, __shfl_down(m, off));
            m = __shfl(m, 0);
            float e = 0.f;
            if (lane < nf) e += __expf(v0 - m);
            if (lane + 64 < nf) e += __expf(v1 - m);
#pragma unroll
            for (int off = 32; off; off >>= 1) e += __shfl_down(e, off);
            if (lane == 0) {
                int b = sb[s];
                int lf = label_family[b];
                wave_loss += __logf(e) + m - slog[s][lf];
            }
        }
        if (lane == 0 && wave_loss != 0.f) atomicAdd(acc_loss, wave_loss);
        __syncthreads();
    }
}

// ---------------- finalize ----------------
__global__ void finalize_kernel(const float* __restrict__ accs,
                                const int* __restrict__ active_cnt,
                                float* __restrict__ out) {
    out[0] = (accs[0] + accs[1]) / (8192.0f + (float)(*active_cnt));
}

extern "C" void kernel_launch(void* const* d_in, const int* in_sizes, int n_in,
                              void* d_out, int out_size, void* d_ws, size_t ws_size,
                              hipStream_t stream) {
    (void)in_sizes; (void)n_in; (void)out_size; (void)ws_size;
    const float* output       = (const float*)d_in[0];
    const int*   label_clan   = (const int*)d_in[1];
    const int*   label_family = (const int*)d_in[2];
    const int*   fc           = (const int*)d_in[3];
    const float* W_clan       = (const float*)d_in[4];
    const float* b_clan       = (const float*)d_in[5];
    const float* W_fam        = (const float*)d_in[6];
    const float* b_fam        = (const float*)d_in[7];
    float* out = (float*)d_out;

    char* ws = (char*)d_ws;
    const size_t OFF_X    = 0;                                   // 8192*256*4   = 8,388,608
    const size_t OFF_LOG  = OFF_X + (size_t)B_SZ * D_SZ * 4;     // 8192*600*4   = 19,660,800
    const size_t OFF_CNT  = OFF_LOG + (size_t)B_SZ * NC * 4;     // 600*4 -> pad 2560
    const size_t OFF_LIST = OFF_CNT + 2560;                      // 600*64*4     = 153,600
    const size_t OFF_ACC  = OFF_LIST + (size_t)NC * CAP * 4;     // 2 floats + int
    float* x      = (float*)(ws + OFF_X);
    float* logits = (float*)(ws + OFF_LOG);
    int*   cnt    = (int*)(ws + OFF_CNT);
    int*   list   = (int*)(ws + OFF_LIST);
    float* accs   = (float*)(ws + OFF_ACC);
    int*   act    = (int*)(ws + OFF_ACC + 8);

    // zero counters + accumulators (ws is poisoned 0xAA before every call)
    hipMemsetAsync(ws + OFF_CNT, 0, 2560 + (size_t)NC * CAP * 4 + 16, stream);

    mean_kernel<<<B_SZ * D_SZ / 4 / 256, 256, 0, stream>>>(output, x);
    scatter_kernel<<<B_SZ / 256, 256, 0, stream>>>(label_clan, fc, cnt, list, act);
    dim3 gg(B_SZ / BM, (NC + BN - 1) / BN);
    clan_gemm<<<gg, 256, 0, stream>>>(x, W_clan, b_clan, logits);
    clan_loss<<<B_SZ, 256, 0, stream>>>(logits, label_clan, accs);
    family_kernel<<<NC, 256, 0, stream>>>(x, W_fam, b_fam, fc, cnt, list, label_family, accs + 1);
    finalize_kernel<<<1, 1, 0, stream>>>(accs, act, out);
}

// Round 2
// 1067.079 us; speedup vs baseline: 1.0321x; 1.0321x over previous
//
#include <hip/hip_runtime.h>
#include <hip/hip_bf16.h>

#define B_SZ 8192
#define L_SZ 64
#define D_SZ 256
#define NC   600
#define MAXF 128
#define CAP  64     // max samples per clan bucket (expected max ~28 for 8192/600)

// ---------------- mean over L: x[b,d] = mean_l output[b,l,d] ----------------
__global__ __launch_bounds__(256) void mean_kernel(const float* __restrict__ out,
                                                   float* __restrict__ x) {
    int gid = blockIdx.x * 256 + threadIdx.x;      // B*D/4 = 524288 threads
    int b = gid >> 6, d4 = gid & 63;
    const float4* p = (const float4*)(out + (size_t)b * L_SZ * D_SZ) + d4;
    float4 acc = {0.f, 0.f, 0.f, 0.f};
#pragma unroll 8
    for (int l = 0; l < L_SZ; ++l) {
        float4 v = p[(size_t)l * (D_SZ / 4)];
        acc.x += v.x; acc.y += v.y; acc.z += v.z; acc.w += v.w;
    }
    const float s = 1.0f / 64.0f;
    acc.x *= s; acc.y *= s; acc.z *= s; acc.w *= s;
    ((float4*)(x + (size_t)b * D_SZ))[d4] = acc;
}

// ---------------- bucket samples by clan + count active ----------------
__global__ __launch_bounds__(256) void scatter_kernel(const int* __restrict__ label_clan,
                                                      const int* __restrict__ fc,
                                                      int* __restrict__ cnt,
                                                      int* __restrict__ list,
                                                      int* __restrict__ active_cnt) {
    int b = blockIdx.x * 256 + threadIdx.x;        // grid exactly covers 8192
    int cl = label_clan[b];
    int pos = atomicAdd(&cnt[cl], 1);
    if (pos < CAP) list[cl * CAP + pos] = b;
    int act = (fc[cl] > 1) ? 1 : 0;
    unsigned long long ball = __ballot(act);
    if ((threadIdx.x & 63) == 0) atomicAdd(active_cnt, (int)__popcll(ball));
}

// ---------------- fused clan GEMM + CE loss (online LSE), 1 atomic/block ----
// 256 blocks x 256 threads; block owns CBM=32 rows, loops 10 col-tiles of 64.
#define CBM 32
__global__ __launch_bounds__(256) void clan_fused(const float* __restrict__ x,
                                                  const float* __restrict__ Wc,
                                                  const float* __restrict__ bc,
                                                  const int* __restrict__ label_clan,
                                                  float* __restrict__ acc_loss) {
    __shared__ float As[CBM][260];     // 32 x 256 A-panel, pad 260 (33.3 KB)
    __shared__ float Bs[64][68];       // 64 cols x 64-k chunk, pad 68 (17.4 KB)
    __shared__ float redm[CBM][16];
    __shared__ float mrow[CBM], srow[CBM], mnew[CBM], lablog[CBM];
    __shared__ int   labc[CBM];
    int t = threadIdx.x;
    int tx = t & 15, ty = t >> 4;      // cols: tx+16j, rows: ty+16i (strided -> broadcast-friendly)
    int row0 = blockIdx.x * CBM;

    // load A panel 32x256 (coalesced 1KB/row)
#pragma unroll
    for (int rep = 0; rep < 8; ++rep) {
        int idx = t + rep * 256;
        int r = idx >> 6, c4 = idx & 63;
        *(float4*)&As[r][c4 * 4] = *(const float4*)(x + (size_t)(row0 + r) * D_SZ + c4 * 4);
    }
    if (t < CBM) {
        mrow[t] = -1e30f; srow[t] = 0.f; lablog[t] = 0.f;
        labc[t] = label_clan[row0 + t];
    }
    __syncthreads();

    for (int ct = 0; ct < 10; ++ct) {
        int c0 = ct * 64;
        float acc[2][4] = {};
        for (int k0 = 0; k0 < D_SZ; k0 += 64) {
            __syncthreads();           // Bs reuse hazard
#pragma unroll
            for (int rep = 0; rep < 4; ++rep) {
                int idx = t + rep * 256;
                int col = idx >> 4, kq = idx & 15;
                int c = c0 + col;
                float4 v = {0.f, 0.f, 0.f, 0.f};
                if (c < NC) v = *(const float4*)(Wc + (size_t)c * D_SZ + k0 + kq * 4);
                *(float4*)&Bs[col][kq * 4] = v;
            }
            __syncthreads();
#pragma unroll
            for (int kk = 0; kk < 16; ++kk) {
                float4 a0 = *(float4*)&As[ty][k0 + kk * 4];
                float4 a1 = *(float4*)&As[ty + 16][k0 + kk * 4];
                float4 b[4];
#pragma unroll
                for (int j = 0; j < 4; ++j) b[j] = *(float4*)&Bs[tx + 16 * j][kk * 4];
#pragma unroll
                for (int j = 0; j < 4; ++j) {
                    acc[0][j] += a0.x * b[j].x + a0.y * b[j].y + a0.z * b[j].z + a0.w * b[j].w;
                    acc[1][j] += a1.x * b[j].x + a1.y * b[j].y + a1.z * b[j].z + a1.w * b[j].w;
                }
            }
        }
        // bias + mask + label capture
        float lg[2][4];
#pragma unroll
        for (int i = 0; i < 2; ++i) {
            int row = ty + 16 * i;
#pragma unroll
            for (int j = 0; j < 4; ++j) {
                int c = c0 + tx + 16 * j;
                float v = (c < NC) ? acc[i][j] + bc[c] : -1e30f;
                lg[i][j] = v;
                if (c < NC && c == labc[row]) lablog[row] = v;   // unique writer
            }
        }
        // online LSE update for this 64-col tile
#pragma unroll
        for (int i = 0; i < 2; ++i) {
            int row = ty + 16 * i;
            redm[row][tx] = fmaxf(fmaxf(lg[i][0], lg[i][1]), fmaxf(lg[i][2], lg[i][3]));
        }
        __syncthreads();
        if (t < CBM) {
            float tm = redm[t][0];
#pragma unroll
            for (int q = 1; q < 16; ++q) tm = fmaxf(tm, redm[t][q]);
            mnew[t] = fmaxf(mrow[t], tm);
        }
        __syncthreads();
#pragma unroll
        for (int i = 0; i < 2; ++i) {
            int row = ty + 16 * i;
            float mn = mnew[row];
            redm[row][tx] = __expf(lg[i][0] - mn) + __expf(lg[i][1] - mn)
                          + __expf(lg[i][2] - mn) + __expf(lg[i][3] - mn);
        }
        __syncthreads();
        if (t < CBM) {
            float s = 0.f;
#pragma unroll
            for (int q = 0; q < 16; ++q) s += redm[t][q];
            srow[t] = srow[t] * __expf(mrow[t] - mnew[t]) + s;
            mrow[t] = mnew[t];
        }
        // next tile's first __syncthreads() (Bs hazard) orders these updates
    }
    __syncthreads();
    if (t < 64) {
        float loss = 0.f;
        if (t < CBM) loss = __logf(srow[t]) + mrow[t] - lablog[t];
#pragma unroll
        for (int off = 16; off; off >>= 1) loss += __shfl_down(loss, off);
        if (t == 0) atomicAdd(acc_loss, loss);
    }
}

// ---------------- family loss: one block per clan, 1 atomic/block ----------
#define CHUNK 16
__global__ __launch_bounds__(256) void family_kernel(const float* __restrict__ x,
                                                     const float* __restrict__ Wf,
                                                     const float* __restrict__ bf,
                                                     const int* __restrict__ fc,
                                                     const int* __restrict__ cnt,
                                                     const int* __restrict__ list,
                                                     const int* __restrict__ label_family,
                                                     float* __restrict__ acc_loss) {
    int clan = blockIdx.x;
    int nf = fc[clan];
    if (nf <= 1) return;                    // inactive clans contribute 0
    int n = min(cnt[clan], CAP);
    if (n == 0) return;
    __shared__ float sx[CHUNK][D_SZ];
    __shared__ float slog[CHUNK][MAXF];
    __shared__ int sb[CHUNK];
    __shared__ float wl[4];
    int t = threadIdx.x;
    int lane = t & 63, wid = t >> 6;
    const float* Wbase = Wf + (size_t)clan * MAXF * D_SZ;

    float wave_loss = 0.f;
    for (int s0 = 0; s0 < n; s0 += CHUNK) {
        int cn = min(CHUNK, n - s0);
        if (t < cn) sb[t] = list[clan * CAP + s0 + t];
        __syncthreads();
        for (int q = t; q < cn * (D_SZ / 4); q += 256) {
            int s = q >> 6, d4 = q & 63;
            ((float4*)sx[s])[d4] = ((const float4*)(x + (size_t)sb[s] * D_SZ))[d4];
        }
        __syncthreads();
        // logits: wave `wid` handles families f = wid, wid+4, ...
        for (int f = wid; f < nf; f += 4) {
            float4 w = ((const float4*)(Wbase + (size_t)f * D_SZ))[lane];
            float bias = bf[clan * MAXF + f];
            for (int s = 0; s < cn; ++s) {
                float4 xv = ((float4*)sx[s])[lane];
                float p = w.x * xv.x + w.y * xv.y + w.z * xv.z + w.w * xv.w;
#pragma unroll
                for (int off = 32; off; off >>= 1) p += __shfl_down(p, off);
                if (lane == 0) slog[s][f] = p + bias;
            }
        }
        __syncthreads();
        // softmax + nll per sample; wave wid takes samples wid, wid+4, ...
        for (int s = wid; s < cn; s += 4) {
            float v0 = (lane < nf) ? slog[s][lane] : -1e30f;
            float v1 = (lane + 64 < nf) ? slog[s][lane + 64] : -1e30f;
            float m = fmaxf(v0, v1);
#pragma unroll
            for (int off = 32; off; off >>= 1) m = fmaxf(m, __shfl_down(m, off));
            m = __shfl(m, 0);
            float e = 0.f;
            if (lane < nf) e += __expf(v0 - m);
            if (lane + 64 < nf) e += __expf(v1 - m);
#pragma unroll
            for (int off = 32; off; off >>= 1) e += __shfl_down(e, off);
            if (lane == 0) {
                int b = sb[s];
                int lf = label_family[b];
                wave_loss += __logf(e) + m - slog[s][lf];
            }
        }
        __syncthreads();
    }
    if (lane == 0) wl[wid] = wave_loss;
    __syncthreads();
    if (t == 0) {
        float v = wl[0] + wl[1] + wl[2] + wl[3];
        if (v != 0.f) atomicAdd(acc_loss, v);
    }
}

// ---------------- finalize ----------------
__global__ void finalize_kernel(const float* __restrict__ accs,
                                const int* __restrict__ active_cnt,
                                float* __restrict__ out) {
    out[0] = (accs[0] + accs[1]) / (8192.0f + (float)(*active_cnt));
}

extern "C" void kernel_launch(void* const* d_in, const int* in_sizes, int n_in,
                              void* d_out, int out_size, void* d_ws, size_t ws_size,
                              hipStream_t stream) {
    (void)in_sizes; (void)n_in; (void)out_size; (void)ws_size;
    const float* output       = (const float*)d_in[0];
    const int*   label_clan   = (const int*)d_in[1];
    const int*   label_family = (const int*)d_in[2];
    const int*   fc           = (const int*)d_in[3];
    const float* W_clan       = (const float*)d_in[4];
    const float* b_clan       = (const float*)d_in[5];
    const float* W_fam        = (const float*)d_in[6];
    const float* b_fam        = (const float*)d_in[7];
    float* out = (float*)d_out;

    char* ws = (char*)d_ws;
    const size_t OFF_X    = 0;                                   // 8192*256*4 = 8,388,608
    const size_t OFF_CNT  = OFF_X + (size_t)B_SZ * D_SZ * 4;     // 600*4 -> pad 2560
    const size_t OFF_ACC  = OFF_CNT + 2560;                      // 2 floats + 1 int (16 B)
    const size_t OFF_LIST = OFF_ACC + 16;                        // 600*64*4 = 153,600
    float* x      = (float*)(ws + OFF_X);
    int*   cnt    = (int*)(ws + OFF_CNT);
    float* accs   = (float*)(ws + OFF_ACC);
    int*   act    = (int*)(ws + OFF_ACC + 8);
    int*   list   = (int*)(ws + OFF_LIST);

    // zero counters + accumulators (ws is poisoned 0xAA before every call)
    hipMemsetAsync(ws + OFF_CNT, 0, 2560 + 16, stream);

    mean_kernel<<<B_SZ * D_SZ / 4 / 256, 256, 0, stream>>>(output, x);
    scatter_kernel<<<B_SZ / 256, 256, 0, stream>>>(label_clan, fc, cnt, list, act);
    clan_fused<<<B_SZ / CBM, 256, 0, stream>>>(x, W_clan, b_clan, label_clan, accs);
    family_kernel<<<NC, 256, 0, stream>>>(x, W_fam, b_fam, fc, cnt, list, label_family, accs + 1);
    finalize_kernel<<<1, 1, 0, stream>>>(accs, act, out);
}

// Round 3
// 1015.472 us; speedup vs baseline: 1.0845x; 1.0508x over previous
//
#include <hip/hip_runtime.h>
#include <hip/hip_bf16.h>

#define B_SZ 8192
#define L_SZ 64
#define D_SZ 256
#define NC   600
#define MAXF 128
#define CAP  64     // max samples per clan bucket (expected max ~28 for 8192/600)
#define CBM  32     // rows per clan-GEMM block
#define CHUNK 16    // samples staged per family iteration

// ---- kernel 1: mean over L (all 2048 blocks) + clan scatter (blocks 0..31) ----
__global__ __launch_bounds__(256) void mean_scatter(const float* __restrict__ out,
                                                    float* __restrict__ x,
                                                    const int* __restrict__ label_clan,
                                                    const int* __restrict__ fc,
                                                    int* __restrict__ cnt,
                                                    int* __restrict__ list,
                                                    int* __restrict__ active_cnt) {
    int t = threadIdx.x;
    if (blockIdx.x < 32) {              // scatter: 32*256 = 8192 samples
        int b = blockIdx.x * 256 + t;
        int cl = label_clan[b];
        int pos = atomicAdd(&cnt[cl], 1);
        if (pos < CAP) list[cl * CAP + pos] = b;
        int act = (fc[cl] > 1) ? 1 : 0;
        unsigned long long ball = __ballot(act);
        if ((t & 63) == 0) atomicAdd(active_cnt, (int)__popcll(ball));
    }
    int gid = blockIdx.x * 256 + t;     // B*D/4 = 524288 threads
    int b = gid >> 6, d4 = gid & 63;
    const float4* p = (const float4*)(out + (size_t)b * L_SZ * D_SZ) + d4;
    float4 acc = {0.f, 0.f, 0.f, 0.f};
#pragma unroll 8
    for (int l = 0; l < L_SZ; ++l) {
        float4 v = p[(size_t)l * (D_SZ / 4)];
        acc.x += v.x; acc.y += v.y; acc.z += v.z; acc.w += v.w;
    }
    const float s = 1.0f / 64.0f;
    acc.x *= s; acc.y *= s; acc.z *= s; acc.w *= s;
    ((float4*)(x + (size_t)b * D_SZ))[d4] = acc;
}

// ---- kernel 2: clan GEMM+CE (blocks 0..255) and family CE (blocks 256..855) ----
// single shared buffer, sized for the clan branch (53376 B -> 3 blocks/CU)
#define SMEM_FLOATS (53376 / 4)

__device__ void clan_branch(float* smem, int blk,
                            const float* __restrict__ x,
                            const float* __restrict__ Wc,
                            const float* __restrict__ bc,
                            const int* __restrict__ label_clan,
                            float* __restrict__ acc_loss) {
    float (*As)[260] = (float(*)[260])smem;                       // 32*260
    float (*Bs)[68]  = (float(*)[68])(smem + 32 * 260);           // 64*68
    float (*redm)[16] = (float(*)[16])(smem + 32 * 260 + 64 * 68);
    float* mrow   = smem + 32 * 260 + 64 * 68 + 32 * 16;
    float* srow   = mrow + 32;
    float* mnew   = srow + 32;
    float* lablog = mnew + 32;
    int*   labc   = (int*)(lablog + 32);

    int t = threadIdx.x;
    int tx = t & 15, ty = t >> 4;      // cols: tx+16j, rows: ty+16i
    int row0 = blk * CBM;

    // load A panel 32x256 (coalesced 1KB/row)
#pragma unroll
    for (int rep = 0; rep < 8; ++rep) {
        int idx = t + rep * 256;
        int r = idx >> 6, c4 = idx & 63;
        *(float4*)&As[r][c4 * 4] = *(const float4*)(x + (size_t)(row0 + r) * D_SZ + c4 * 4);
    }
    if (t < CBM) {
        mrow[t] = -1e30f; srow[t] = 0.f; lablog[t] = 0.f;
        labc[t] = label_clan[row0 + t];
    }
    __syncthreads();

    for (int ct = 0; ct < 10; ++ct) {
        int c0 = ct * 64;
        float acc[2][4] = {};
        for (int k0 = 0; k0 < D_SZ; k0 += 64) {
            __syncthreads();           // Bs reuse hazard
#pragma unroll
            for (int rep = 0; rep < 4; ++rep) {
                int idx = t + rep * 256;
                int col = idx >> 4, kq = idx & 15;
                int c = c0 + col;
                float4 v = {0.f, 0.f, 0.f, 0.f};
                if (c < NC) v = *(const float4*)(Wc + (size_t)c * D_SZ + k0 + kq * 4);
                *(float4*)&Bs[col][kq * 4] = v;
            }
            __syncthreads();
#pragma unroll
            for (int kk = 0; kk < 16; ++kk) {
                float4 a0 = *(float4*)&As[ty][k0 + kk * 4];
                float4 a1 = *(float4*)&As[ty + 16][k0 + kk * 4];
                float4 b[4];
#pragma unroll
                for (int j = 0; j < 4; ++j) b[j] = *(float4*)&Bs[tx + 16 * j][kk * 4];
#pragma unroll
                for (int j = 0; j < 4; ++j) {
                    acc[0][j] += a0.x * b[j].x + a0.y * b[j].y + a0.z * b[j].z + a0.w * b[j].w;
                    acc[1][j] += a1.x * b[j].x + a1.y * b[j].y + a1.z * b[j].z + a1.w * b[j].w;
                }
            }
        }
        // bias + mask + label capture
        float lg[2][4];
#pragma unroll
        for (int i = 0; i < 2; ++i) {
            int row = ty + 16 * i;
#pragma unroll
            for (int j = 0; j < 4; ++j) {
                int c = c0 + tx + 16 * j;
                float v = (c < NC) ? acc[i][j] + bc[c] : -1e30f;
                lg[i][j] = v;
                if (c < NC && c == labc[row]) lablog[row] = v;   // unique writer
            }
        }
        // online LSE update for this 64-col tile
#pragma unroll
        for (int i = 0; i < 2; ++i) {
            int row = ty + 16 * i;
            redm[row][tx] = fmaxf(fmaxf(lg[i][0], lg[i][1]), fmaxf(lg[i][2], lg[i][3]));
        }
        __syncthreads();
        if (t < CBM) {
            float tm = redm[t][0];
#pragma unroll
            for (int q = 1; q < 16; ++q) tm = fmaxf(tm, redm[t][q]);
            mnew[t] = fmaxf(mrow[t], tm);
        }
        __syncthreads();
#pragma unroll
        for (int i = 0; i < 2; ++i) {
            int row = ty + 16 * i;
            float mn = mnew[row];
            redm[row][tx] = __expf(lg[i][0] - mn) + __expf(lg[i][1] - mn)
                          + __expf(lg[i][2] - mn) + __expf(lg[i][3] - mn);
        }
        __syncthreads();
        if (t < CBM) {
            float s = 0.f;
#pragma unroll
            for (int q = 0; q < 16; ++q) s += redm[t][q];
            srow[t] = srow[t] * __expf(mrow[t] - mnew[t]) + s;
            mrow[t] = mnew[t];
        }
        // next tile's first __syncthreads() (Bs hazard) orders these updates
    }
    __syncthreads();
    if (t < 64) {
        float loss = 0.f;
        if (t < CBM) loss = __logf(srow[t]) + mrow[t] - lablog[t];
#pragma unroll
        for (int off = 16; off; off >>= 1) loss += __shfl_down(loss, off);
        if (t == 0) atomicAdd(acc_loss, loss);
    }
}

__device__ void family_branch(float* smem, int clan,
                              const float* __restrict__ x,
                              const float* __restrict__ Wf,
                              const float* __restrict__ bf,
                              const int* __restrict__ fc,
                              const int* __restrict__ cnt,
                              const int* __restrict__ list,
                              const int* __restrict__ label_family,
                              float* __restrict__ acc_loss) {
    int nf = fc[clan];
    if (nf <= 1) return;                    // inactive clans contribute 0
    int n = min(cnt[clan], CAP);
    if (n == 0) return;
    float (*sx)[D_SZ]   = (float(*)[D_SZ])smem;                    // 16*256
    float (*slog)[MAXF] = (float(*)[MAXF])(smem + CHUNK * D_SZ);   // 16*128
    int*   sb = (int*)(smem + CHUNK * D_SZ + CHUNK * MAXF);
    float* wl = (float*)(sb + CHUNK);

    int t = threadIdx.x;
    int lane = t & 63, wid = t >> 6;
    const float* Wbase = Wf + (size_t)clan * MAXF * D_SZ;

    float wave_loss = 0.f;
    for (int s0 = 0; s0 < n; s0 += CHUNK) {
        int cn = min(CHUNK, n - s0);
        if (t < cn) sb[t] = list[clan * CAP + s0 + t];
        __syncthreads();
        for (int q = t; q < cn * (D_SZ / 4); q += 256) {
            int s = q >> 6, d4 = q & 63;
            ((float4*)sx[s])[d4] = ((const float4*)(x + (size_t)sb[s] * D_SZ))[d4];
        }
        __syncthreads();
        // logits: wave `wid` handles families f = wid, wid+4, ...
        for (int f = wid; f < nf; f += 4) {
            float4 w = ((const float4*)(Wbase + (size_t)f * D_SZ))[lane];
            float bias = bf[clan * MAXF + f];
            for (int s = 0; s < cn; ++s) {
                float4 xv = ((float4*)sx[s])[lane];
                float p = w.x * xv.x + w.y * xv.y + w.z * xv.z + w.w * xv.w;
#pragma unroll
                for (int off = 32; off; off >>= 1) p += __shfl_down(p, off);
                if (lane == 0) slog[s][f] = p + bias;
            }
        }
        __syncthreads();
        // softmax + nll per sample; wave wid takes samples wid, wid+4, ...
        for (int s = wid; s < cn; s += 4) {
            float v0 = (lane < nf) ? slog[s][lane] : -1e30f;
            float v1 = (lane + 64 < nf) ? slog[s][lane + 64] : -1e30f;
            float m = fmaxf(v0, v1);
#pragma unroll
            for (int off = 32; off; off >>= 1) m = fmaxf(m, __shfl_down(m, off));
            m = __shfl(m, 0);
            float e = 0.f;
            if (lane < nf) e += __expf(v0 - m);
            if (lane + 64 < nf) e += __expf(v1 - m);
#pragma unroll
            for (int off = 32; off; off >>= 1) e += __shfl_down(e, off);
            if (lane == 0) {
                int b = sb[s];
                int lf = label_family[b];
                wave_loss += __logf(e) + m - slog[s][lf];
            }
        }
        __syncthreads();
    }
    if (lane == 0) wl[wid] = wave_loss;
    __syncthreads();
    if (t == 0) {
        float v = wl[0] + wl[1] + wl[2] + wl[3];
        if (v != 0.f) atomicAdd(acc_loss, v);
    }
}

__global__ __launch_bounds__(256) void clan_family(const float* __restrict__ x,
                                                   const float* __restrict__ Wc,
                                                   const float* __restrict__ bc,
                                                   const int* __restrict__ label_clan,
                                                   const float* __restrict__ Wf,
                                                   const float* __restrict__ bf,
                                                   const int* __restrict__ fc,
                                                   const int* __restrict__ cnt,
                                                   const int* __restrict__ list,
                                                   const int* __restrict__ label_family,
                                                   float* __restrict__ accs) {
    __shared__ float smem[SMEM_FLOATS];
    if (blockIdx.x < 256) {
        clan_branch(smem, blockIdx.x, x, Wc, bc, label_clan, accs);
    } else {
        family_branch(smem, blockIdx.x - 256, x, Wf, bf, fc, cnt, list, label_family, accs + 1);
    }
}

// ---------------- finalize ----------------
__global__ void finalize_kernel(const float* __restrict__ accs,
                                const int* __restrict__ active_cnt,
                                float* __restrict__ out) {
    out[0] = (accs[0] + accs[1]) / (8192.0f + (float)(*active_cnt));
}

extern "C" void kernel_launch(void* const* d_in, const int* in_sizes, int n_in,
                              void* d_out, int out_size, void* d_ws, size_t ws_size,
                              hipStream_t stream) {
    (void)in_sizes; (void)n_in; (void)out_size; (void)ws_size;
    const float* output       = (const float*)d_in[0];
    const int*   label_clan   = (const int*)d_in[1];
    const int*   label_family = (const int*)d_in[2];
    const int*   fc           = (const int*)d_in[3];
    const float* W_clan       = (const float*)d_in[4];
    const float* b_clan       = (const float*)d_in[5];
    const float* W_fam        = (const float*)d_in[6];
    const float* b_fam        = (const float*)d_in[7];
    float* out = (float*)d_out;

    char* ws = (char*)d_ws;
    const size_t OFF_X    = 0;                                   // 8192*256*4 = 8,388,608
    const size_t OFF_CNT  = OFF_X + (size_t)B_SZ * D_SZ * 4;     // 600*4 -> pad 2560
    const size_t OFF_ACC  = OFF_CNT + 2560;                      // 2 floats + 1 int (16 B)
    const size_t OFF_LIST = OFF_ACC + 16;                        // 600*64*4 = 153,600
    float* x      = (float*)(ws + OFF_X);
    int*   cnt    = (int*)(ws + OFF_CNT);
    float* accs   = (float*)(ws + OFF_ACC);
    int*   act    = (int*)(ws + OFF_ACC + 8);
    int*   list   = (int*)(ws + OFF_LIST);

    // zero counters + accumulators (ws is poisoned 0xAA before every call)
    hipMemsetAsync(ws + OFF_CNT, 0, 2560 + 16, stream);

    mean_scatter<<<B_SZ * D_SZ / 4 / 256, 256, 0, stream>>>(output, x, label_clan, fc,
                                                            cnt, list, act);
    clan_family<<<256 + NC, 256, 0, stream>>>(x, W_clan, b_clan, label_clan,
                                              W_fam, b_fam, fc, cnt, list, label_family, accs);
    finalize_kernel<<<1, 1, 0, stream>>>(accs, act, out);
}